// Round 11
// baseline (176.961 us; speedup 1.0000x reference)
//
#include <hip/hip_runtime.h>

// VectorQuantizer: X [16384][128] f32, E [128][8192] f32
// out (f32 flat): quantized [16384*128], encodings [16384*8192], indices [16384], loss [1]
#define D 128
#define K 8192
#define N 16384
#define BM 32                 // rows per block (grid 512 -> 2 blocks/CU)
#define TILES 64              // 32-col tiles per wave (4 waves x 32 cols x 64 = 8192)
#define GRP 4                 // tiles per gate-group
#define THREADS 256
#define CAND_CAP 1024
#define DELTA 0.5f
#define RMIN_INIT 0xFF800000u // fsort(+inf); NOT 0xFFFFFFFF (decodes to NaN)

typedef __attribute__((ext_vector_type(4))) float f32x4;
typedef __attribute__((ext_vector_type(16))) float f32x16;
typedef __attribute__((ext_vector_type(8))) short short8;

__device__ __forceinline__ unsigned short f2bf(float f) {
    unsigned int b = __float_as_uint(f);
    return (unsigned short)((b + 0x7FFFu + ((b >> 16) & 1u)) >> 16);
}
__device__ __forceinline__ unsigned int fsort(float f) {
    unsigned int b = __float_as_uint(f);
    return b ^ ((unsigned int)((int)b >> 31) | 0x80000000u);
}
__device__ __forceinline__ float funsort(unsigned int u) {
    return __uint_as_float((u & 0x80000000u) ? (u ^ 0x80000000u) : ~u);
}

// ---- prep: E -> bf16 transposed e1t[k][d], f32 transposed e2t[k][d], enorm ----
__global__ __launch_bounds__(256) void prep_kernel(const float* __restrict__ E,
        unsigned short* __restrict__ e1t, float* __restrict__ e2t,
        float* __restrict__ enorm) {
    __shared__ float esum[8][32];
    const int t = threadIdx.x;
    const int kl = t & 31, dg = t >> 5;
    const int k = blockIdx.x * 32 + kl;
    float s = 0.f;
    __align__(16) unsigned short tmpb[16];
    __align__(16) float tmpf[16];
#pragma unroll
    for (int j = 0; j < 16; ++j) {
        float v = E[(size_t)(dg * 16 + j) * K + k];
        s += v * v;
        tmpb[j] = f2bf(v);
        tmpf[j] = v;
    }
    *(f32x4*)(e1t + (size_t)k * D + dg * 16) = *(const f32x4*)tmpb;
    *(f32x4*)(e1t + (size_t)k * D + dg * 16 + 8) = *(const f32x4*)(tmpb + 8);
    if (e2t) {
#pragma unroll
        for (int q = 0; q < 4; ++q)
            *(f32x4*)(e2t + (size_t)k * D + dg * 16 + 4 * q) = *(const f32x4*)(tmpf + 4 * q);
    }
    esum[dg][kl] = s;
    __syncthreads();
    if (t < 32) {
        float e = 0.f;
#pragma unroll
        for (int g = 0; g < 8; ++g) e += esum[g][t];
        enorm[blockIdx.x * 32 + t] = e;
    }
}

// ---- main: barrier-free direct-global MFMA sweep.
// Per wave, per 32-col tile: {8 B-frag loads + enorm load} -> fence ->
// {prev tile's NT zero-stores} -> MFMA (waits only its older loads; stores
// stay in flight). Gate+push once per GRP tiles. No LDS staging, no in-loop
// barriers -> waves free-run, store stalls overlap other waves' compute. ----
template<int E2T>
__global__ __launch_bounds__(THREADS, 2) void main_kernel(
        const float* __restrict__ X, const float* __restrict__ E,
        const unsigned short* __restrict__ e1t, const float* __restrict__ e2t,
        const float* __restrict__ enorm, float* __restrict__ out,
        float* __restrict__ partials) {
    __shared__ unsigned long long cand[CAND_CAP];   // 8 KB
    __shared__ unsigned long long best[BM];
    __shared__ unsigned int rmin[BM];
    __shared__ float red[THREADS];
    __shared__ int candn;

    const int t = threadIdx.x;
    const int wid = t >> 6, l = t & 63;
    const int l31 = l & 31, lh = l >> 5;
    const int wn = wid;                  // wave's col-slice within each 128-col stripe
    const int rowbase = blockIdx.x * BM;

    float* qout = out;
    float* enc = out + (size_t)N * D;
    float* idxout = enc + (size_t)N * K;

    if (t < BM) { rmin[t] = RMIN_INIT; best[t] = ~0ull; }
    if (t == 0) candn = 0;
    __syncthreads();

    // A fragments: bf16(x) for the block's 32 rows (all 4 waves identical rows)
    short8 afr[8];
    {
        const int row = rowbase + l31;
#pragma unroll
        for (int ks = 0; ks < 8; ++ks) {
            const float* xp = X + (size_t)row * D + ks * 16 + lh * 8;
            f32x4 v0 = *(const f32x4*)xp;
            f32x4 v1 = *(const f32x4*)(xp + 4);
            short8 a;
            a[0] = (short)f2bf(v0[0]); a[1] = (short)f2bf(v0[1]);
            a[2] = (short)f2bf(v0[2]); a[3] = (short)f2bf(v0[3]);
            a[4] = (short)f2bf(v1[0]); a[5] = (short)f2bf(v1[1]);
            a[6] = (short)f2bf(v1[2]); a[7] = (short)f2bf(v1[3]);
            afr[ks] = a;
        }
    }

    const f32x4 z = {0.f, 0.f, 0.f, 0.f};
    const int srow = l >> 3, scol = (l & 7) * 4;   // zero-store lane mapping

    for (int cg = 0; cg < TILES / GRP; ++cg) {
        f32x16 dsv[GRP];   // compile-time indexed (unrolled) -> registers
#pragma unroll
        for (int g = 0; g < GRP; ++g) {
            const int ti = cg * GRP + g;
            const int col0 = ti * 128 + wn * 32;
            const int c = col0 + l31;

            // ---- loads FIRST (must be older than the stores below) ----
            short8 bf[8];
            const unsigned short* bp = e1t + (size_t)c * D + lh * 8;
#pragma unroll
            for (int ks = 0; ks < 8; ++ks)
                bf[ks] = *(const short8*)(bp + ks * 16);
            const float en = enorm[c];
            asm volatile("" ::: "memory");   // compiler fence: no store hoisting

            // ---- previous tile's one-hot zero-fill (NT, stays in flight) ----
            if (cg > 0 || g > 0) {
                const int pcol0 = col0 - 128;
#pragma unroll
                for (int i = 0; i < 4; ++i)
                    __builtin_nontemporal_store(z,
                        (f32x4*)(enc + (size_t)(rowbase + i * 8 + srow) * K + pcol0 + scol));
            }

            // ---- MFMA: waits only its own (older) loads ----
#pragma unroll
            for (int r = 0; r < 16; ++r) dsv[g][r] = 0.f;
#pragma unroll
            for (int ks = 0; ks < 8; ++ks)
                dsv[g] = __builtin_amdgcn_mfma_f32_32x32x16_bf16(afr[ks], bf[ks], dsv[g], 0, 0, 0);
#pragma unroll
            for (int r = 0; r < 16; ++r)
                dsv[g][r] = fmaf(-2.f, dsv[g][r], en);   // d~ = en - 2*sim
        }

        // ---- per-group gate: one shuffle reduce per GRP tiles ----
        float lmin[16];
#pragma unroll
        for (int r = 0; r < 16; ++r)
            lmin[r] = fminf(fminf(dsv[0][r], dsv[1][r]),
                            fminf(dsv[2][r], dsv[3][r]));
#pragma unroll
        for (int m = 1; m <= 16; m <<= 1)
#pragma unroll
            for (int r = 0; r < 16; ++r)
                lmin[r] = fminf(lmin[r], __shfl_xor(lmin[r], m, 64));

        float thrv[16];
#pragma unroll
        for (int q = 0; q < 4; ++q) {
            const int base = 8 * q + 4 * lh;
            uint4 rv = *(const uint4*)&rmin[base];
            thrv[4 * q + 0] = funsort(rv.x);
            thrv[4 * q + 1] = funsort(rv.y);
            thrv[4 * q + 2] = funsort(rv.z);
            thrv[4 * q + 3] = funsort(rv.w);
        }

#pragma unroll
        for (int r = 0; r < 16; ++r) {
            const int ro = (r & 3) + 8 * (r >> 2) + 4 * lh;
            const float te = fminf(thrv[r], lmin[r]) + DELTA;
#pragma unroll
            for (int g = 0; g < GRP; ++g) {
                if (dsv[g][r] < te) {
                    const int col = (cg * GRP + g) * 128 + wn * 32 + l31;
                    int ci = atomicAdd(&candn, 1);
                    if (ci < CAND_CAP)
                        cand[ci] = ((unsigned long long)fsort(dsv[g][r]) << 32) |
                                   ((unsigned long long)ro << 13) | (unsigned)col;
                }
            }
            if (l31 == 0 && lmin[r] < thrv[r])
                atomicMin(&rmin[ro], fsort(lmin[r]));
        }
    }

    {   // last tile's zero-fill
        const int pcol0 = (TILES - 1) * 128 + wn * 32;
#pragma unroll
        for (int i = 0; i < 4; ++i)
            __builtin_nontemporal_store(z,
                (f32x4*)(enc + (size_t)(rowbase + i * 8 + srow) * K + pcol0 + scol));
    }

    __syncthreads();   // FULL drain: zero-fill stores complete; rmin/cand final

    // ---- exact f32 verification of surviving candidates ----
    {
        int n = candn; if (n > CAND_CAP) n = CAND_CAP;
        for (int i = wid; i < n; i += 4) {     // one wave per candidate
            const unsigned long long e = cand[i];
            const float dta = funsort((unsigned int)(e >> 32));
            const int ro = (int)((e >> 13) & 63u);
            const int col = (int)(e & 8191u);
            if (dta < funsort(rmin[ro]) + DELTA) {
                const int row = rowbase + ro;
                float x0 = X[(size_t)row * D + l];
                float x1 = X[(size_t)row * D + 64 + l];
                float e0, e1;
                if (E2T) {
                    e0 = e2t[(size_t)col * D + l];
                    e1 = e2t[(size_t)col * D + 64 + l];
                } else {
                    e0 = E[(size_t)l * K + col];
                    e1 = E[(size_t)(l + 64) * K + col];
                }
                float s = x0 * e0 + x1 * e1;
#pragma unroll
                for (int m = 1; m <= 32; m <<= 1) s += __shfl_xor(s, m, 64);
                if (l == 0) {
                    float dtx = enorm[col] - 2.f * s;
                    atomicMin(&best[ro],
                        ((unsigned long long)fsort(dtx) << 32) | (unsigned)col);
                }
            }
        }
    }
    __syncthreads();

    // ---- outputs: indices, one-hot scatter, quantized, loss partial ----
    if (t < BM) {
        const int k = (int)(best[t] & 8191ull);
        idxout[rowbase + t] = (float)k;
        __builtin_nontemporal_store(1.0f, &enc[(size_t)(rowbase + t) * K + k]);
    }

    const int rr = t >> 3, sL = t & 7;
    const int row = rowbase + rr;
    const int kb = (int)(best[rr] & 8191ull);
    float part = 0.f;
#pragma unroll
    for (int j = 0; j < 4; ++j) {
        const int d0 = sL * 16 + 4 * j;
        f32x4 xv = *(const f32x4*)(X + (size_t)row * D + d0);
        f32x4 ev;
        if (E2T) {
            ev = *(const f32x4*)(e2t + (size_t)kb * D + d0);
        } else {
#pragma unroll
            for (int u = 0; u < 4; ++u) ev[u] = E[(size_t)(d0 + u) * K + kb];
        }
        f32x4 qv;
#pragma unroll
        for (int u = 0; u < 4; ++u) {
            float df = ev[u] - xv[u];
            qv[u] = xv[u] + df;
            part += df * df;
        }
        *(f32x4*)(qout + (size_t)row * D + d0) = qv;
    }
    red[t] = part;
    __syncthreads();
#pragma unroll
    for (int off = THREADS / 2; off > 0; off >>= 1) {
        if (t < off) red[t] += red[t + off];
        __syncthreads();
    }
    if (t == 0) partials[blockIdx.x] = red[0];
}

__global__ __launch_bounds__(256) void loss_kernel(const float* __restrict__ partials,
                                                   float* __restrict__ out) {
    __shared__ float red[256];
    const int t = threadIdx.x;
    red[t] = partials[t] + partials[t + 256];
    __syncthreads();
    for (int off = 128; off > 0; off >>= 1) {
        if (t < off) red[t] += red[t + off];
        __syncthreads();
    }
    if (t == 0) {
        float mean = red[0] / (float)((size_t)N * D);
        out[(size_t)N * D + (size_t)N * K + N] = mean + 0.25f * mean;
    }
}

extern "C" void kernel_launch(void* const* d_in, const int* in_sizes, int n_in,
                              void* d_out, int out_size, void* d_ws, size_t ws_size,
                              hipStream_t stream) {
    const float* X = (const float*)d_in[0];
    const float* E = (const float*)d_in[1];
    float* out = (float*)d_out;
    char* ws = (char*)d_ws;

    const size_t E1T_B = (size_t)K * D * 2;          // 2 MB
    const size_t E2T_B = (size_t)K * D * 4;          // 4 MB
    const bool use_e2t = ws_size >= E1T_B + E2T_B + 64 * 1024;

    unsigned short* e1t = (unsigned short*)ws;
    float* e2t; float* enorm; float* partials;
    if (use_e2t) {
        e2t = (float*)(ws + E1T_B);
        enorm = (float*)(ws + E1T_B + E2T_B);
        partials = enorm + K;
    } else {
        e2t = nullptr;
        enorm = (float*)(ws + E1T_B);
        partials = enorm + K;
    }

    hipLaunchKernelGGL(prep_kernel, dim3(K / 32), dim3(256), 0, stream,
                       E, e1t, e2t, enorm);
    if (use_e2t)
        hipLaunchKernelGGL((main_kernel<1>), dim3(N / BM), dim3(THREADS), 0, stream,
                           X, E, e1t, e2t, enorm, out, partials);
    else
        hipLaunchKernelGGL((main_kernel<0>), dim3(N / BM), dim3(THREADS), 0, stream,
                           X, E, e1t, e2t, enorm, out, partials);
    hipLaunchKernelGGL(loss_kernel, dim3(1), dim3(256), 0, stream, partials, out);
}